// Round 12
// baseline (4075.590 us; speedup 1.0000x reference)
//
#include <hip/hip_runtime.h>

// ModalVerlet: B=16, M=64, T=48000. ILP-2 scan: each lane carries TWO
// independent chains (same mode m of two batches), interleaved per-step.
//
// Why: R5-R11 all land at 71-85 cyc/step regardless of issue count (27-33)
// or chain length (12-22) — a single wave with ILP=1 cannot hide its
// dependent-use / trans / LDS stalls, and 240 CUs sit idle. Two independent
// chains per lane let chain B's ops fill chain A's stall slots.
//
// Per-chain math is bit-identical to R8 (absmax 2.0): step =
//   rNew=rcp(aPrev); hs=fma(phe,fe,g2); cz=fma(mom2C,z,hs); kl=fma(m2g2,rU,cz);
//   W=fma(CAu,u,z); zn=fma(CAGB,kl,W); un=fma(Fd,u,kl); e=exp2(zn); a=ePrev+1.
// p moved to storers: p_s = Gd*(u_s + u_{s+1}) (exact).
//
// 8 blocks x 320 threads: wave 0 = dual scan; waves 1-4 = storers
// (bb = (wid-1)&1 selects batch, wpar = (wid-1)>>1 selects tile parity),
// R8's phase-split protocol per batch verbatim. LDS: per-batch 4-slot ring
// of (z,u) pairs, 2 x 64KB = 128KB.

#define NB 16
#define NM 64
#define NT 48000
#define SPI 32
#define NITER (NT / SPI) // 1500
#define NSLOT 4

__global__ void __launch_bounds__(320, 1) modal_scan_kernel(
    const float* __restrict__ y0,
    const float* __restrict__ omega,
    const float* __restrict__ sigma,
    const float* __restrict__ gamma,
    const float* __restrict__ Phi_e,
    const float* __restrict__ fe_points,
    float* __restrict__ y_out)
{
    const int b0  = 2 * blockIdx.x;      // chain A batch
    const int b1  = b0 + 1;              // chain B batch
    const int wid = threadIdx.x >> 6;
    const int m   = threadIdx.x & 63;

    __shared__ float4 lzu[2][NSLOT][SPI / 2][NM]; // [batch][slot][pair][mode]; 128KB

    const float k    = 1.0f / 48000.0f;
    const float k2   = 0.5f * k;
    const float invC = 0.34657359027997264f; // ln(2)/2
    const float C    = 2.885390081777927f;   // 2*log2(e)

    if (wid == 0) {
        // ---------------- dual scan wave ----------------
        // chain A consts
        const float omA  = omega[b0 * NM + m];
        const float sgA  = sigma[b0 * NM + m];
        const float gA   = gamma[b0];
        const float pheA = Phi_e[b0 * NM + m];
        const float om2A = omA * omA;
        const float g2A  = gA * gA;
        const float EA     = 1.0f - k * sgA;
        const float dinvA  = 1.0f / (1.0f + k * sgA);
        const float AA     = k * EA;
        const float BcA    = k * k2;
        const float FdA    = EA * dinvA;
        const float GdA    = k2 * dinvA;
        const float AGBA   = AA * GdA + BcA;
        const float m2g2A  = -2.0f * g2A;
        const float CAGBA  = C * AGBA;
        const float mom2CA = -om2A * invC;
        const float GdF1A  = GdA * (1.0f + FdA);
        const float CAuA   = (C * AA) * GdF1A;

        // chain B consts
        const float omB  = omega[b1 * NM + m];
        const float sgB  = sigma[b1 * NM + m];
        const float gB   = gamma[b1];
        const float pheB = Phi_e[b1 * NM + m];
        const float om2B = omB * omB;
        const float g2B  = gB * gB;
        const float EB     = 1.0f - k * sgB;
        const float dinvB  = 1.0f / (1.0f + k * sgB);
        const float AB     = k * EB;
        const float BcB    = k * k2;
        const float FdB    = EB * dinvB;
        const float GdB    = k2 * dinvB;
        const float AGBB   = AB * GdB + BcB;
        const float m2g2B  = -2.0f * g2B;
        const float CAGBB  = C * AGBB;
        const float mom2CB = -om2B * invC;
        const float GdF1B  = GdB * (1.0f + FdB);
        const float CAuB   = (C * AB) * GdF1B;

        const float4* feA = reinterpret_cast<const float4*>(fe_points + (size_t)b0 * NT);
        const float4* feB = reinterpret_cast<const float4*>(fe_points + (size_t)b1 * NT);

        float4 bufA0[8], bufA1[8], bufB0[8], bufB1[8];
#pragma unroll
        for (int i = 0; i < 8; ++i) { bufA0[i] = feA[i];     bufB0[i] = feB[i]; }
#pragma unroll
        for (int i = 0; i < 8; ++i) { bufA1[i] = feA[8 + i]; bufB1[i] = feB[8 + i]; }

        // ---- preamble: state 0 of both chains ----
        float zA = C * y0[b0 * 2 * NM + m];
        float zB = C * y0[b1 * 2 * NM + m];
        float ePrevA = __builtin_amdgcn_exp2f(zA);
        float ePrevB = __builtin_amdgcn_exp2f(zB);
        float aPrevA = ePrevA + 1.0f;
        float aPrevB = ePrevB + 1.0f;
        float rUA = __builtin_amdgcn_rcpf(aPrevA);
        float rUB = __builtin_amdgcn_rcpf(aPrevB);
        float uA, uB;
        {
            float p0A = y0[b0 * 2 * NM + NM + m];
            float hsA = fmaf(pheA, bufA0[0].x, g2A);
            float czA = fmaf(mom2CA, zA, hsA);
            float c0A = fmaf(m2g2A, rUA, czA);
            uA = fmaf(-GdA, c0A, p0A) / GdF1A;

            float p0B = y0[b1 * 2 * NM + NM + m];
            float hsB = fmaf(pheB, bufB0[0].x, g2B);
            float czB = fmaf(mom2CB, zB, hsB);
            float c0B = fmaf(m2g2B, rUB, czB);
            uB = fmaf(-GdB, c0B, p0B) / GdF1B;
        }

#define STEPA(FE) {                                       \
    float rNew = __builtin_amdgcn_rcpf(aPrevA);           \
    float hs = fmaf(pheA, (FE), g2A);                     \
    float cz = fmaf(mom2CA, zA, hs);                      \
    float kl = fmaf(m2g2A, rUA, cz);                      \
    float W  = fmaf(CAuA, uA, zA);                        \
    float zn = fmaf(CAGBA, kl, W);                        \
    float un = fmaf(FdA, uA, kl);                         \
    float e  = __builtin_amdgcn_exp2f(zn);                \
    aPrevA = ePrevA + 1.0f;                               \
    ePrevA = e; rUA = rNew; zA = zn; uA = un; }

#define STEPB(FE) {                                       \
    float rNew = __builtin_amdgcn_rcpf(aPrevB);           \
    float hs = fmaf(pheB, (FE), g2B);                     \
    float cz = fmaf(mom2CB, zB, hs);                      \
    float kl = fmaf(m2g2B, rUB, cz);                      \
    float W  = fmaf(CAuB, uB, zB);                        \
    float zn = fmaf(CAGBB, kl, W);                        \
    float un = fmaf(FdB, uB, kl);                         \
    float e  = __builtin_amdgcn_exp2f(zn);                \
    aPrevB = ePrevB + 1.0f;                               \
    ePrevB = e; rUB = rNew; zB = zn; uB = un; }

#define STEP2AB(FA0, FB0, FA1, FB1, TP) {                 \
    float zaA = zA, uaA = uA; STEPA(FA0);                 \
    float zaB = zB, uaB = uB; STEPB(FB0);                 \
    float zbA = zA, ubA = uA; STEPA(FA1);                 \
    float zbB = zB, ubB = uB; STEPB(FB1);                 \
    sA[(TP) * NM] = make_float4(zaA, uaA, zbA, ubA);      \
    sB[(TP) * NM] = make_float4(zaB, uaB, zbB, ubB); }

#define STEP32AB(BA, BB) \
    STEP2AB(BA[0].x, BB[0].x, BA[0].y, BB[0].y, 0);  \
    STEP2AB(BA[0].z, BB[0].z, BA[0].w, BB[0].w, 1);  \
    STEP2AB(BA[1].x, BB[1].x, BA[1].y, BB[1].y, 2);  \
    STEP2AB(BA[1].z, BB[1].z, BA[1].w, BB[1].w, 3);  \
    STEP2AB(BA[2].x, BB[2].x, BA[2].y, BB[2].y, 4);  \
    STEP2AB(BA[2].z, BB[2].z, BA[2].w, BB[2].w, 5);  \
    STEP2AB(BA[3].x, BB[3].x, BA[3].y, BB[3].y, 6);  \
    STEP2AB(BA[3].z, BB[3].z, BA[3].w, BB[3].w, 7);  \
    STEP2AB(BA[4].x, BB[4].x, BA[4].y, BB[4].y, 8);  \
    STEP2AB(BA[4].z, BB[4].z, BA[4].w, BB[4].w, 9);  \
    STEP2AB(BA[5].x, BB[5].x, BA[5].y, BB[5].y, 10); \
    STEP2AB(BA[5].z, BB[5].z, BA[5].w, BB[5].w, 11); \
    STEP2AB(BA[6].x, BB[6].x, BA[6].y, BB[6].y, 12); \
    STEP2AB(BA[6].z, BB[6].z, BA[6].w, BB[6].w, 13); \
    STEP2AB(BA[7].x, BB[7].x, BA[7].y, BB[7].y, 14); \
    STEP2AB(BA[7].z, BB[7].z, BA[7].w, BB[7].w, 15);

        for (int j = 0; j < NITER; j += 2) {
            float4* sA = &lzu[0][j & 3][0][m];
            float4* sB = &lzu[1][j & 3][0][m];
            STEP32AB(bufA0, bufB0);
            {
                const int jn = (j + 2 < NITER) ? (j + 2) : j;
#pragma unroll
                for (int i = 0; i < 8; ++i) { bufA0[i] = feA[8 * jn + i]; bufB0[i] = feB[8 * jn + i]; }
            }
            __syncthreads();

            sA = &lzu[0][(j + 1) & 3][0][m];
            sB = &lzu[1][(j + 1) & 3][0][m];
            STEP32AB(bufA1, bufB1);
            {
                const int jn = (j + 3 < NITER) ? (j + 3) : (j + 1);
#pragma unroll
                for (int i = 0; i < 8; ++i) { bufA1[i] = feA[8 * jn + i]; bufB1[i] = feB[8 * jn + i]; }
            }
            __syncthreads();
        }
        // pseudo-entries for u_{NT} (slot (NITER&3)==0, entry 0, .y)
        lzu[0][0][0][m] = make_float4(0.0f, uA, 0.0f, 0.0f);
        lzu[1][0][0][m] = make_float4(0.0f, uB, 0.0f, 0.0f);
        __syncthreads();   // barrier #NITER+1 (matched by storers)
#undef STEP32AB
#undef STEP2AB
#undef STEPB
#undef STEPA
    } else {
        // ---------------- storer waves (wid 1..4) ----------------
        const int idx  = wid - 1;
        const int bb   = idx & 1;        // which batch's ring
        const int wpar = idx >> 1;       // tile parity
        const int gb   = b0 + bb;

        const float sg   = sigma[gb * NM + m];
        const float dinv = 1.0f / (1.0f + k * sg);
        const float Gd   = k2 * dinv;

        float* yql = y_out + ((size_t)gb * 2 * NM + m) * (size_t)NT;
        float* ypl = yql + (size_t)NM * NT;

        auto HALF = [&](int tile, int half) {
            const float4* sp  = &lzu[bb][tile & 3][0][m];
            const float4* spn = &lzu[bb][(tile + 1) & 3][0][m];
            float4* dq = reinterpret_cast<float4*>(yql + (size_t)SPI * tile) + half * 4;
            float4* dp = reinterpret_cast<float4*>(ypl + (size_t)SPI * tile) + half * 4;
#pragma unroll
            for (int i = half * 4; i < half * 4 + 4; ++i) {
                float4 va = sp[(2 * i) * NM];
                float4 vb = sp[(2 * i + 1) * NM];
                float  u2 = (i < 7) ? sp[(2 * i + 2) * NM].y : spn[0].y;
                dq[i - half * 4] = make_float4(invC * va.x, invC * va.z,
                                               invC * vb.x, invC * vb.z);
                dp[i - half * 4] = make_float4(Gd * (va.y + va.w), Gd * (va.w + vb.y),
                                               Gd * (vb.y + vb.w), Gd * (vb.w + u2));
            }
        };

        for (int j = 0; j < NITER; ++j) {
            __syncthreads();           // publishes tile j (both batches)
            if ((j & 1) == wpar) {
                HALF(j, 0);            // phase A of my tile j
            } else if (j >= 1) {
                HALF(j - 1, 1);        // phase B of my tile j-1
            }
        }
        __syncthreads();               // publishes pseudo-entry (u_NT)
        if (((NITER - 1) & 1) == wpar) {
            HALF(NITER - 1, 1);        // phase B of the final tile
        }
    }
}

// w[b,t] = sum_m Phi_o[b,m] * y[b,m,t]  (fully parallel, memory/L3-bound)
__global__ void __launch_bounds__(256) w_kernel(
    const float* __restrict__ y,
    const float* __restrict__ Phi_o,
    float* __restrict__ w)
{
    const int b  = blockIdx.y;
    const int t4 = blockIdx.x * 256 + threadIdx.x;
    if (t4 >= NT / 4) return;

    const float4* yb = reinterpret_cast<const float4*>(y + (size_t)b * 2 * NM * NT);
    const float*  po = Phi_o + b * NM;

    float4 acc = make_float4(0.f, 0.f, 0.f, 0.f);
    #pragma unroll 8
    for (int mm = 0; mm < NM; ++mm) {
        float  c = po[mm];
        float4 v = yb[mm * (NT / 4) + t4];
        acc.x = fmaf(c, v.x, acc.x);
        acc.y = fmaf(c, v.y, acc.y);
        acc.z = fmaf(c, v.z, acc.z);
        acc.w = fmaf(c, v.w, acc.w);
    }
    reinterpret_cast<float4*>(w + (size_t)b * NT)[t4] = acc;
}

extern "C" void kernel_launch(void* const* d_in, const int* in_sizes, int n_in,
                              void* d_out, int out_size, void* d_ws, size_t ws_size,
                              hipStream_t stream)
{
    // inputs: 0=fs, 1=num_samples, 2=y0, 3=omega, 4=sigma, 5=gamma,
    //         6=Phi_e, 7=Phi_o, 8=fe_points
    const float* y0    = (const float*)d_in[2];
    const float* omega = (const float*)d_in[3];
    const float* sigma = (const float*)d_in[4];
    const float* gamma = (const float*)d_in[5];
    const float* Phi_e = (const float*)d_in[6];
    const float* Phi_o = (const float*)d_in[7];
    const float* fe    = (const float*)d_in[8];

    float* y_out = (float*)d_out;                    // (B, 2M, T)
    float* w_out = y_out + (size_t)NB * 2 * NM * NT; // (B, T)

    modal_scan_kernel<<<NB / 2, 320, 0, stream>>>(y0, omega, sigma, gamma, Phi_e, fe, y_out);

    dim3 grid((NT / 4 + 255) / 256, NB);
    w_kernel<<<grid, 256, 0, stream>>>(y_out, Phi_o, w_out);
}

// Round 13
// 1489.680 us; speedup vs baseline: 2.7359x; 2.7359x over previous
//
#include <hip/hip_runtime.h>

// ModalVerlet: B=16, M=64, T=48000. 1 scan wave + 2 storer waves (R8 skeleton).
//
// Model (fits R4-R12): a SOLO wave issues ~1 instr / ~5 cyc (dependent-use
// latency exposed; no co-resident wave to fill gaps). Wall time = serial chain
// latency = instrs-per-step x ~5cyc. So this round minimizes instrs/step:
//  - r = rcp(exp2(z)+1) computed once per TWO steps (pair): force uses r at
//    lag-1 (even) / lag-2 (odd) instead of uniform lag-1. Extra error
//    ~g2*|dq/step| ~ 1e-6, k-integrated -> negligible vs scheme drift.
//  - SPI 32->64 (NSLOT=2 ring, 64KB): halves barrier/loop/refill cost per step.
//    Boundary u via lub[2][NM] side channel (R7-proven): p_s = Gd*(u_s+u_{s+1}),
//    last u of tile j = scan's u at tile end, written before barrier j.
// Pair body (2 steps): 12 fma + exp2 + add + rcp + 1 ds_write_b128 (+0.5 fe
// amortized) ~ 18 instr -> ~9/step (R8: ~14/step).
//
// Storers: 2 waves, alternate whole tiles (parity w), work in interval j on
// slot j&1 while scan fills slot (j+1)&1 -> no overlap. q=invC*z, p=Gd*(u+u').

#define NB 16
#define NM 64
#define NT 48000
#define SPI 64
#define NITER (NT / SPI) // 750

__global__ void __launch_bounds__(192, 1) modal_scan_kernel(
    const float* __restrict__ y0,
    const float* __restrict__ omega,
    const float* __restrict__ sigma,
    const float* __restrict__ gamma,
    const float* __restrict__ Phi_e,
    const float* __restrict__ fe_points,
    float* __restrict__ y_out)
{
    const int b   = blockIdx.x;
    const int wid = threadIdx.x >> 6;
    const int m   = threadIdx.x & 63;

    __shared__ float4 lzu[2][SPI / 2][NM]; // per slot: (z_s,u_s,z_{s+1},u_{s+1}); 64KB
    __shared__ float  lub[2][NM];          // boundary u at tile end

    const float k    = 1.0f / 48000.0f;
    const float k2   = 0.5f * k;
    const float invC = 0.34657359027997264f; // ln(2)/2

    if (wid == 0) {
        // ---------------- scan wave ----------------
        const float om  = omega[b * NM + m];
        const float sg  = sigma[b * NM + m];
        const float g   = gamma[b];
        const float phe = Phi_e[b * NM + m];
        const float om2 = om * om;
        const float g2  = g * g;

        const float E    = 1.0f - k * sg;
        const float dinv = 1.0f / (1.0f + k * sg);
        const float A    = k * E;
        const float Bc   = k * k2;
        const float Fd   = E * dinv;
        const float Gd   = k2 * dinv;
        const float AGB  = A * Gd + Bc;
        const float m2g2 = -2.0f * g2;

        const float C    = 2.885390081777927f;   // 2*log2(e)
        const float CAGB = C * AGB;
        const float mom2C = -om2 * invC;
        const float GdF1 = Gd * (1.0f + Fd);
        const float CAu  = (C * A) * GdF1;

        const float q0v = y0[b * 2 * NM + m];
        const float p0v = y0[b * 2 * NM + NM + m];

        const float4* fe4 = reinterpret_cast<const float4*>(fe_points + (size_t)b * NT);

        float4 bufA[8], bufB[8];
#pragma unroll
        for (int i = 0; i < 8; ++i) bufA[i] = fe4[i];      // fe[0..31]
#pragma unroll
        for (int i = 0; i < 8; ++i) bufB[i] = fe4[8 + i];  // fe[32..63]

        // ---- preamble: state 0 ----
        float z = C * q0v;
        float r;
        float u;
        {
            float e0 = __builtin_amdgcn_exp2f(z);
            r = __builtin_amdgcn_rcpf(e0 + 1.0f);          // r(z_0)
            float hs0 = fmaf(phe, bufA[0].x, g2);
            float cz0 = fmaf(mom2C, z, hs0);
            float c0  = fmaf(m2g2, r, cz0);
            u = fmaf(-Gd, c0, p0v) / GdF1;                 // u_0
        }

        // PAIR: writes states (s, s+1), advances to s+2. One exp2+add+rcp per
        // pair: r refreshed from z_{s+1}, used by next pair (lag-1 then lag-2).
#define PAIR(F0, F1, SP, TP) {                            \
    float za = z, ua = u;                                 \
    float hs0 = fmaf(phe, (F0), g2);                      \
    float cz0 = fmaf(mom2C, z, hs0);                      \
    float kl0 = fmaf(m2g2, r, cz0);                       \
    float W0  = fmaf(CAu, u, z);                          \
    float zn  = fmaf(CAGB, kl0, W0);                      \
    float un  = fmaf(Fd, u, kl0);                         \
    float en  = __builtin_amdgcn_exp2f(zn);               \
    float hs1 = fmaf(phe, (F1), g2);                      \
    float cz1 = fmaf(mom2C, zn, hs1);                     \
    float kl1 = fmaf(m2g2, r, cz1);                       \
    float W1  = fmaf(CAu, un, zn);                        \
    z = fmaf(CAGB, kl1, W1);                              \
    u = fmaf(Fd, un, kl1);                                \
    float an  = en + 1.0f;                                \
    r = __builtin_amdgcn_rcpf(an);                        \
    (SP)[(TP) * NM] = make_float4(za, ua, zn, un); }

#define PAIR2(F4, SP, TP) \
    PAIR((F4).x, (F4).y, SP, TP); PAIR((F4).z, (F4).w, SP, (TP) + 1)

#define PAIR16(BUF, SP, TPB) \
    PAIR2(BUF[0], SP, (TPB) + 0);  PAIR2(BUF[1], SP, (TPB) + 2);  \
    PAIR2(BUF[2], SP, (TPB) + 4);  PAIR2(BUF[3], SP, (TPB) + 6);  \
    PAIR2(BUF[4], SP, (TPB) + 8);  PAIR2(BUF[5], SP, (TPB) + 10); \
    PAIR2(BUF[6], SP, (TPB) + 12); PAIR2(BUF[7], SP, (TPB) + 14);

#define TILE(JT, SP) {                                            \
    const int jn = ((JT) + 1 < NITER) ? ((JT) + 1) : (JT);        \
    PAIR16(bufA, SP, 0);                                          \
    _Pragma("unroll")                                             \
    for (int i = 0; i < 8; ++i) bufA[i] = fe4[16 * jn + i];       \
    PAIR16(bufB, SP, 16);                                         \
    _Pragma("unroll")                                             \
    for (int i = 0; i < 8; ++i) bufB[i] = fe4[16 * jn + 8 + i];   \
    lub[(JT) & 1][m] = u;                                         \
    __syncthreads(); }

        float4* sp0 = &lzu[0][0][m];
        float4* sp1 = &lzu[1][0][m];
        for (int j = 0; j < NITER; j += 2) {
            TILE(j, sp0);
            TILE(j + 1, sp1);
        }
#undef TILE
#undef PAIR16
#undef PAIR2
#undef PAIR
    } else {
        // ---------------- storer waves (wpar = 0,1) ----------------
        const int wpar = wid - 1;
        const float sg   = sigma[b * NM + m];
        const float dinv = 1.0f / (1.0f + k * sg);
        const float Gd   = k2 * dinv;

        float* yql = y_out + ((size_t)b * 2 * NM + m) * (size_t)NT;
        float* ypl = yql + (size_t)NM * NT;

        for (int j = 0; j < NITER; ++j) {
            __syncthreads();            // publishes tile j (slot j&1) + lub
            if ((j & 1) != wpar) continue;

            const float4* sp = &lzu[j & 1][0][m];
            const float  ulast = lub[j & 1][m];
            float4* dq = reinterpret_cast<float4*>(yql + (size_t)SPI * j);
            float4* dp = reinterpret_cast<float4*>(ypl + (size_t)SPI * j);
#pragma unroll
            for (int i = 0; i < 16; ++i) {
                float4 va = sp[(2 * i) * NM];
                float4 vb = sp[(2 * i + 1) * NM];
                float  u2 = (i < 15) ? sp[(2 * i + 2) * NM].y : ulast;
                dq[i] = make_float4(invC * va.x, invC * va.z,
                                    invC * vb.x, invC * vb.z);
                dp[i] = make_float4(Gd * (va.y + va.w), Gd * (va.w + vb.y),
                                    Gd * (vb.y + vb.w), Gd * (vb.w + u2));
            }
        }
    }
}

// w[b,t] = sum_m Phi_o[b,m] * y[b,m,t]  (fully parallel, memory/L3-bound)
__global__ void __launch_bounds__(256) w_kernel(
    const float* __restrict__ y,
    const float* __restrict__ Phi_o,
    float* __restrict__ w)
{
    const int b  = blockIdx.y;
    const int t4 = blockIdx.x * 256 + threadIdx.x;
    if (t4 >= NT / 4) return;

    const float4* yb = reinterpret_cast<const float4*>(y + (size_t)b * 2 * NM * NT);
    const float*  po = Phi_o + b * NM;

    float4 acc = make_float4(0.f, 0.f, 0.f, 0.f);
    #pragma unroll 8
    for (int mm = 0; mm < NM; ++mm) {
        float  c = po[mm];
        float4 v = yb[mm * (NT / 4) + t4];
        acc.x = fmaf(c, v.x, acc.x);
        acc.y = fmaf(c, v.y, acc.y);
        acc.z = fmaf(c, v.z, acc.z);
        acc.w = fmaf(c, v.w, acc.w);
    }
    reinterpret_cast<float4*>(w + (size_t)b * NT)[t4] = acc;
}

extern "C" void kernel_launch(void* const* d_in, const int* in_sizes, int n_in,
                              void* d_out, int out_size, void* d_ws, size_t ws_size,
                              hipStream_t stream)
{
    // inputs: 0=fs, 1=num_samples, 2=y0, 3=omega, 4=sigma, 5=gamma,
    //         6=Phi_e, 7=Phi_o, 8=fe_points
    const float* y0    = (const float*)d_in[2];
    const float* omega = (const float*)d_in[3];
    const float* sigma = (const float*)d_in[4];
    const float* gamma = (const float*)d_in[5];
    const float* Phi_e = (const float*)d_in[6];
    const float* Phi_o = (const float*)d_in[7];
    const float* fe    = (const float*)d_in[8];

    float* y_out = (float*)d_out;                    // (B, 2M, T)
    float* w_out = y_out + (size_t)NB * 2 * NM * NT; // (B, T)

    modal_scan_kernel<<<NB, 192, 0, stream>>>(y0, omega, sigma, gamma, Phi_e, fe, y_out);

    dim3 grid((NT / 4 + 255) / 256, NB);
    w_kernel<<<grid, 256, 0, stream>>>(y_out, Phi_o, w_out);
}